// Round 2
// baseline (102.041 us; speedup 1.0000x reference)
//
#include <hip/hip_runtime.h>

#define IC 3
#define OCH 16
#define IDD 16
#define IHH 32
#define IWW 32
#define ODD 31
#define OHH 63
#define OWW 63
#define NB 32

static __device__ __forceinline__ float4 fma4(float s, float4 w, float4 a) {
    a.x = fmaf(s, w.x, a.x);
    a.y = fmaf(s, w.y, a.y);
    a.z = fmaf(s, w.z, a.z);
    a.w = fmaf(s, w.w, a.w);
    return a;
}

// Fused ConvTranspose3d(3->16,k3,s2,p1) + channel-LSE + x*sigmoid(x+3)/6 - bias, clip.
// Thread tile: 2(oh) x 8(ow) = 16 outputs at one od. oc chunked by 4 (one b128 of
// weights per kernel position feeds 4 ow-pairs -> 4x LDS reuse vs round-1 kernel).
// exp-sum carried across oc chunks (no max subtraction: |conv| << 88, fp32-safe).
__global__ __launch_bounds__(256) void convt_lse_kernel(
    const float* __restrict__ x, const float* __restrict__ w,
    const float* __restrict__ bias, float* __restrict__ out)
{
    // LDS weights: [kd*3+ic][pos(kh*3+kw)][oc] -- oc contiguous for ds_read_b128
    __shared__ float wl[9 * 9 * OCH];
    for (int idx = threadIdx.x; idx < 9 * 9 * OCH; idx += 256) {
        int oc  = idx & 15;
        int r   = idx >> 4;        // (kd*3+ic)*9 + pos
        int pos = r % 9;
        int icd = r / 9;           // kd*3 + ic
        int kd  = icd / 3;
        int ic  = icd % 3;
        wl[idx] = w[(ic * OCH + oc) * 27 + kd * 9 + pos];
    }
    __syncthreads();

    const int t  = threadIdx.x & 7;     // ow tile: ow = 8t .. 8t+7 (pairs P = 4t..4t+3)
    const int i  = threadIdx.x >> 3;    // oh pair: oh = 2i, 2i+1
    const int od = blockIdx.x;          // [0,31)
    const int b  = blockIdx.y;          // [0,32)

    // wave-uniform tap set for this od
    int ntap, kd0, id0, kd1 = 0, id1 = 0;
    if (od & 1) { ntap = 2; kd0 = 0; id0 = (od + 1) >> 1; kd1 = 2; id1 = (od - 1) >> 1; }
    else        { ntap = 1; kd0 = 1; id0 = od >> 1; }

    const int ih0 = i;
    const int ih1 = min(i + 1, IHH - 1);   // clamped: feeds only unstored oh=63
    const int iwb = 4 * t;                 // input cols iwb..iwb+4
    const int iwe = min(iwb + 4, IWW - 1); // clamped: feeds only unstored ow=63

    float s[2][8];
    #pragma unroll
    for (int r = 0; r < 2; ++r)
        #pragma unroll
        for (int cc = 0; cc < 8; ++cc) s[r][cc] = 0.0f;

    #pragma unroll 1
    for (int c = 0; c < 4; ++c) {          // oc chunk: oc = 4c .. 4c+3
        float4 acc[2][8];
        #pragma unroll
        for (int r = 0; r < 2; ++r)
            #pragma unroll
            for (int cc = 0; cc < 8; ++cc) acc[r][cc] = make_float4(0.f, 0.f, 0.f, 0.f);

        #pragma unroll 1
        for (int tp = 0; tp < ntap; ++tp) {
            const int kd = tp ? kd1 : kd0;
            const int id = tp ? id1 : id0;
            #pragma unroll
            for (int ic = 0; ic < IC; ++ic) {
                const float* __restrict__ xp = x + (((b * IC + ic) * IDD + id) << 10);
                const float4 a0 = *(const float4*)(xp + ih0 * IWW + iwb);
                const float  e0 = xp[ih0 * IWW + iwe];
                const float4 a1 = *(const float4*)(xp + ih1 * IWW + iwb);
                const float  e1 = xp[ih1 * IWW + iwe];
                const float r0[5] = {a0.x, a0.y, a0.z, a0.w, e0};
                const float r1[5] = {a1.x, a1.y, a1.z, a1.w, e1};

                const float* wbase = &wl[(kd * 3 + ic) * 9 * OCH + c * 4];
                float4 W[9];
                #pragma unroll
                for (int p = 0; p < 9; ++p) W[p] = *(const float4*)(wbase + p * OCH);

                #pragma unroll
                for (int q = 0; q < 4; ++q) {
                    const float x00 = r0[q], x01 = r0[q + 1];
                    const float x10 = r1[q], x11 = r1[q + 1];
                    // (even oh, even ow): kh=1,kw=1
                    acc[0][2*q]   = fma4(x00, W[4], acc[0][2*q]);
                    // (even, odd): kw=0 uses x[.][+1], kw=2 uses x[.][0]
                    acc[0][2*q+1] = fma4(x01, W[3], fma4(x00, W[5], acc[0][2*q+1]));
                    // (odd, even): kh=0 uses x[+1][.], kh=2 uses x[0][.]
                    acc[1][2*q]   = fma4(x10, W[1], fma4(x00, W[7], acc[1][2*q]));
                    // (odd, odd)
                    acc[1][2*q+1] = fma4(x11, W[0], fma4(x10, W[2],
                                    fma4(x01, W[6], fma4(x00, W[8], acc[1][2*q+1]))));
                }
            }
        }

        // fold chunk into running exp-sum (no max-sub: values are small, fp32-safe)
        #pragma unroll
        for (int r = 0; r < 2; ++r)
            #pragma unroll
            for (int cc = 0; cc < 8; ++cc) {
                const float4 a = acc[r][cc];
                s[r][cc] += __expf(a.x) + __expf(a.y) + __expf(a.z) + __expf(a.w);
            }
    }

    // epilogue: v = log(sum_exp); hs = v*sigmoid(v+3)/6; clip(hs - bias)
    const float bv    = bias[0];
    const int   obase = (b * ODD + od) * OHH;
    #pragma unroll
    for (int r = 0; r < 2; ++r) {
        const int oh = 2 * i + r;
        if (oh >= OHH) continue;
        #pragma unroll
        for (int cc = 0; cc < 8; ++cc) {
            const int ow = 8 * t + cc;
            if (ow >= OWW) continue;
            const float v  = __logf(s[r][cc]);
            const float hs = v / (6.0f * (1.0f + __expf(-(v + 3.0f))));
            const float rs = fminf(1.0f, fmaxf(-1.0f, hs - bv));
            out[(obase + oh) * OWW + ow] = rs;
        }
    }
}

extern "C" void kernel_launch(void* const* d_in, const int* in_sizes, int n_in,
                              void* d_out, int out_size, void* d_ws, size_t ws_size,
                              hipStream_t stream) {
    const float* x    = (const float*)d_in[0];
    const float* w    = (const float*)d_in[1];
    const float* bias = (const float*)d_in[2];
    float* out        = (float*)d_out;

    dim3 grid(ODD, NB);   // od x batch; 992 blocks of 256 threads
    dim3 block(256);
    convt_lse_kernel<<<grid, block, 0, stream>>>(x, w, bias, out);
}